// Round 2
// baseline (409.005 us; speedup 1.0000x reference)
//
#include <hip/hip_runtime.h>

// LSTM classifier fused kernel, round 2. B=2048, T=256, F=64, H=128.
// 256 blocks x 512 threads, 8 batch rows/block, bf16 MFMA 16x16x32.
// Round-2 structure:
//  - wave w computes ALL 4 gates for H-cols w*16..w*16+15 (nt index = gate)
//    -> gates never leave registers (no gates-LDS round trip).
//  - A operand ([x_t | h_{t-1}], K=192) stored in MFMA-fragment order:
//    tile kt at elem kt*512 + lane*8 + j -> ds_read_b128 at lane*16B,
//    conflict-free. Double-buffered -> ONE __syncthreads per step.
//  - elementwise spread over all 64 lanes via __shfl_xor(32) (quads 2,3
//    take the r=2,3 accumulator rows of quads 0,1). c stays in registers.

#define Bsz   2048
#define Tlen  256
#define Fdim  64
#define Hdim  128
#define BB    8
#define NTHREADS 512
#define TILE_E 512            // elems per kt tile (64 lanes x 8)
#define NKT   6               // kt 0,1 = x (K 0..63), kt 2..5 = h (K 64..191)
#define BUF_E (NKT * TILE_E)  // 3072 bf16 = 6 KB per buffer

using bf16x8 = __attribute__((ext_vector_type(8))) __bf16;
using f32x4  = __attribute__((ext_vector_type(4))) float;

__device__ __forceinline__ float fast_rcp(float x) {
#if __has_builtin(__builtin_amdgcn_rcpf)
    return __builtin_amdgcn_rcpf(x);
#else
    return 1.0f / x;
#endif
}
__device__ __forceinline__ float fast_exp2(float x) {
#if __has_builtin(__builtin_amdgcn_exp2f)
    return __builtin_amdgcn_exp2f(x);
#else
    return exp2f(x);
#endif
}
__device__ __forceinline__ float fsig(float x) {
    return fast_rcp(1.0f + fast_exp2(-1.4426950408889634f * x));
}
__device__ __forceinline__ float ftanh(float x) {
    float e = fast_exp2(-2.8853900817779268f * x);   // exp(-2x)
    return (1.0f - e) * fast_rcp(1.0f + e);
}

__global__ __launch_bounds__(NTHREADS, 2)
void lstm_fused(const float* __restrict__ x,
                const float* __restrict__ W_ih,
                const float* __restrict__ W_hh,
                const float* __restrict__ b_ih,
                const float* __restrict__ b_hh,
                const float* __restrict__ W1,
                const float* __restrict__ b1,
                const float* __restrict__ W2,
                const float* __restrict__ b2,
                float* __restrict__ out)
{
    __shared__ __bf16 Abuf[2][BUF_E];      // 12 KB, fragment-order A operand
    __shared__ float  hlast[BB * Hdim];    // 4 KB fp32 h_T for the head
    __shared__ float  zbuf[BB * 32];       // head hidden

    const int tid  = threadIdx.x;
    const int w    = tid >> 6;             // wave 0..7
    const int lane = tid & 63;
    const int quad = lane >> 4;
    const int l16  = lane & 15;
    const int b0   = blockIdx.x * BB;

    // ---- B fragments: 6 kt x 4 gates, register-resident (96 VGPR) ----
    // lane holds B[k = kt*32 + quad*8 + j][n = g*128 + w*16 + l16]
    bf16x8 bw[NKT][4];
    #pragma unroll
    for (int kt = 0; kt < NKT; ++kt) {
        const int k0 = kt * 32 + quad * 8;
        #pragma unroll
        for (int g = 0; g < 4; ++g) {
            const int n = g * Hdim + w * 16 + l16;
            const float* p = (kt < 2) ? (W_ih + (size_t)n * Fdim + k0)
                                      : (W_hh + (size_t)n * Hdim + (k0 - Fdim));
            float4 lo = *(const float4*)p;
            float4 hi = *(const float4*)(p + 4);
            bf16x8 r;
            r[0]=(__bf16)lo.x; r[1]=(__bf16)lo.y; r[2]=(__bf16)lo.z; r[3]=(__bf16)lo.w;
            r[4]=(__bf16)hi.x; r[5]=(__bf16)hi.y; r[6]=(__bf16)hi.z; r[7]=(__bf16)hi.w;
            bw[kt][g] = r;
        }
    }
    float biasv[4];
    #pragma unroll
    for (int g = 0; g < 4; ++g) {
        const int n = g * Hdim + w * 16 + l16;
        biasv[g] = b_ih[n] + b_hh[n];
    }

    // ---- x staging map: tid<256 -> (row=tid&7, featpair fp=tid>>3) ----
    const bool sx_on  = tid < 256;
    const int  sx_row = tid & 7;
    const int  sx_fp  = (tid >> 3) & 31;
    const float* xrp  = x + (size_t)(b0 + sx_row) * (Tlen * Fdim) + 2 * sx_fp;
    // frag elem for feat k0=2*fp: kt=fp/16, quadk=(fp%16)/4, jj=2*(fp%4)
    const int sx_elem = (sx_fp >> 4) * TILE_E
                      + ((((sx_fp >> 2) & 3) * 16 + sx_row) * 8) + 2 * (sx_fp & 3);

    // ---- elementwise map: lane owns rows er0, er0+1 at H-col hc ----
    const int er0 = (quad < 2) ? quad * 4 : (quad - 2) * 4 + 2;
    const int hc  = w * 16 + l16;          // 0..127
    const int hw_elem = (2 + (hc >> 5)) * TILE_E
                      + ((((hc >> 3) & 3) * 16 + er0) * 8) + (hc & 7);

    // ---- init: zero both buffers (h0=0, pad rows 0), stage x_0 ----
    for (int i = tid; i < 2 * BUF_E; i += NTHREADS)
        ((__bf16*)Abuf)[i] = (__bf16)0.0f;
    float2 xpre = make_float2(0.f, 0.f);
    if (sx_on) xpre = *(const float2*)xrp;             // x_0
    __syncthreads();
    if (sx_on) {
        Abuf[0][sx_elem]     = (__bf16)xpre.x;
        Abuf[0][sx_elem + 1] = (__bf16)xpre.y;
        xpre = *(const float2*)(xrp + Fdim);           // x_1
    }
    __syncthreads();

    float cc0 = 0.f, cc1 = 0.f;

    #pragma unroll 2
    for (int t = 0; t < Tlen; ++t) {
        const int p = t & 1;
        const __bf16* rb   = Abuf[p];
        __bf16*       wbuf = (__bf16*)Abuf[1 - p];

        // A fragments: conflict-free b128 at lane*16B
        bf16x8 af[NKT];
        #pragma unroll
        for (int kt = 0; kt < NKT; ++kt)
            af[kt] = *(const bf16x8*)&rb[kt * TILE_E + lane * 8];

        // prefetch x_{t+2} (consumed next iteration)
        float2 xnext = make_float2(0.f, 0.f);
        if (sx_on && (t + 2) < Tlen)
            xnext = *(const float2*)(xrp + (size_t)(t + 2) * Fdim);

        // 24 MFMA: 4 independent gate chains x 6 kt
        f32x4 acc[4];
        #pragma unroll
        for (int g = 0; g < 4; ++g)
            acc[g] = (f32x4){biasv[g], biasv[g], biasv[g], biasv[g]};
        #pragma unroll
        for (int kt = 0; kt < NKT; ++kt) {
            #pragma unroll
            for (int g = 0; g < 4; ++g)
                acc[g] = __builtin_amdgcn_mfma_f32_16x16x32_bf16(af[kt], bw[kt][g], acc[g], 0, 0, 0);
        }

        // spread rows: quads 2,3 take r=2,3 cells of quads 0,1
        float ga[4][2];
        #pragma unroll
        for (int g = 0; g < 4; ++g) {
            float s2 = __shfl_xor(acc[g][2], 32);
            float s3 = __shfl_xor(acc[g][3], 32);
            ga[g][0] = (quad < 2) ? acc[g][0] : s2;
            ga[g][1] = (quad < 2) ? acc[g][1] : s3;
        }

        // elementwise: 2 cells/lane, c in registers, h -> buf[1-p]
        #pragma unroll
        for (int s = 0; s < 2; ++s) {
            float iv = fsig(ga[0][s]);
            float fv = fsig(ga[1][s]);
            float gv = ftanh(ga[2][s]);
            float ov = fsig(ga[3][s]);
            float c  = fv * (s ? cc1 : cc0) + iv * gv;
            if (s) cc1 = c; else cc0 = c;
            float h  = ov * ftanh(c);
            wbuf[hw_elem + 8 * s] = (__bf16)h;
            if (t == Tlen - 1) hlast[(er0 + s) * Hdim + hc] = h;
        }

        // stage x_{t+1} into the buffer step t+1 will read
        if (sx_on && (t + 1) < Tlen) {
            wbuf[sx_elem]     = (__bf16)xpre.x;
            wbuf[sx_elem + 1] = (__bf16)xpre.y;
        }
        xpre = xnext;
        __syncthreads();   // the ONLY barrier per step
    }

    // ---- head: z = relu(h @ W1^T + b1); out = sigmoid(z @ W2^T + b2) ----
    if (tid < 256) {
        const int b = tid >> 5, n = tid & 31;
        const float4* w4 = (const float4*)(W1 + n * Hdim);
        const float4* h4 = (const float4*)(hlast + b * Hdim);
        float s = b1[n];
        #pragma unroll
        for (int kk = 0; kk < Hdim / 4; ++kk) {
            float4 wv = w4[kk];
            float4 hv = h4[kk];
            s += wv.x * hv.x + wv.y * hv.y + wv.z * hv.z + wv.w * hv.w;
        }
        zbuf[b * 32 + n] = fmaxf(s, 0.0f);
    }
    __syncthreads();
    if (tid < 8) {
        float s = b2[0];
        #pragma unroll
        for (int n = 0; n < 32; ++n) s += zbuf[tid * 32 + n] * W2[n];
        out[b0 + tid] = fsig(s);
    }
}

extern "C" void kernel_launch(void* const* d_in, const int* in_sizes, int n_in,
                              void* d_out, int out_size, void* d_ws, size_t ws_size,
                              hipStream_t stream) {
    const float* x    = (const float*)d_in[0];
    const float* W_ih = (const float*)d_in[1];
    const float* W_hh = (const float*)d_in[2];
    const float* b_ih = (const float*)d_in[3];
    const float* b_hh = (const float*)d_in[4];
    const float* W1   = (const float*)d_in[5];
    const float* b1   = (const float*)d_in[6];
    const float* W2   = (const float*)d_in[7];
    const float* b2   = (const float*)d_in[8];
    float* out = (float*)d_out;

    dim3 grid(Bsz / BB), block(NTHREADS);
    lstm_fused<<<grid, block, 0, stream>>>(x, W_ih, W_hh, b_ih, b_hh, W1, b1, W2, b2, out);
}